// Round 2
// baseline (278.668 us; speedup 1.0000x reference)
//
#include <hip/hip_runtime.h>
#include <stdint.h>

// MultiHeadCrossAttention: B=4, Nq=1024, Nk=2048, QUERY_DIM=1024, KEY_DIM=768, H=16, D=64
// Inputs/outputs are FLOAT32 (harness). Internally fp16 MFMA with f32 accumulate:
//   0) cvt: f32 -> fp16 copies of query/key/value/Wq/Wk/Wv/Wo in ws
//   1) Q = (query @ Wq^T + bq) * 0.125  -> ws fp16 [bh][1024][64]
//   2) K = key @ Wk^T + bk              -> ws fp16 [bh][2048][64]
//   3) V = value @ Wv^T + bv            -> ws fp16 [bh][64][2048]  (d-major, transposed)
//   4) flash attention                  -> ws fp16 [4096][1024]
//   5) out = AO @ Wo^T + bo             -> d_out (f32)

typedef __attribute__((ext_vector_type(4))) float f32x4;
typedef __attribute__((ext_vector_type(8))) _Float16 half8;   // 4 VGPRs — MFMA A/B frag
typedef __attribute__((ext_vector_type(4))) _Float16 half4;
typedef __attribute__((ext_vector_type(4))) short short4v;
typedef unsigned short u16;

__device__ __forceinline__ u16 f2h(float f){
  _Float16 h = (_Float16)f;                       // v_cvt_f16_f32, RNE
  return __builtin_bit_cast(unsigned short, h);
}

__device__ __forceinline__ void gload16(const void* g, void* lds){
  __builtin_amdgcn_global_load_lds((const __attribute__((address_space(1))) void*)g,
                                   (__attribute__((address_space(3))) void*)lds, 16, 0, 0);
}

// ---------- f32 -> fp16 pre-convert (7 segments) ----------
struct Seg { const float* s; u16* d; int n4; };
struct Cvt7 { Seg seg[7]; };

__global__ __launch_bounds__(256) void cvt_f32_f16(Cvt7 a){
  Seg sg = a.seg[blockIdx.y];
  const long stride = (long)gridDim.x * 256;
  for (long i = (long)blockIdx.x*256 + threadIdx.x; i < sg.n4; i += stride){
    f32x4 v = *(const f32x4*)(sg.s + i*4);
    short4v h;
    h[0] = (short)f2h(v[0]); h[1] = (short)f2h(v[1]);
    h[2] = (short)f2h(v[2]); h[3] = (short)f2h(v[3]);
    *(short4v*)(sg.d + i*4) = h;
  }
}

// Stage R rows x 128 bytes (64 fp16/row) global->LDS with 16B-chunk XOR swizzle:
// LDS slot (r, b) holds global byte (r, b ^ ((r&7)<<4)). Readers apply the same XOR.
// Linear LDS dest (wave-uniform base + lane*16, as global_load_lds requires); the
// permutation is applied on the per-lane GLOBAL source address (guide rule #21).
template<int R>
__device__ __forceinline__ void stage_tile(const char* gbase, long gstride, char* lds, int tid){
  const int w = tid >> 6, lane = tid & 63;
  #pragma unroll
  for (int it = 0; it < R/32; ++it){           // (R*128/16)/256 chunks per thread
    int c  = (it*4 + w)*64 + lane;             // 16B chunk id
    int r  = c >> 3;                           // row (8 chunks per row)
    int bs = (c & 7) << 4;                     // byte slot within row
    int sb = bs ^ ((r & 7) << 4);              // inverse-swizzled source byte
    gload16(gbase + (long)r*gstride + sb, lds + (it*4 + w)*1024);
  }
}

// C = A @ Bt^T + bias (Bt is [N][K] row-major, i.e. torch Linear weight), fp16 in.
// N fixed = 1024. 128x128 tile, BK=64, 4 waves (2x2), 16x16x32 f16 MFMA, f32 acc.
// LAYOUT 1: out16[((b*16+h)<<logS | s)*64 + d]   (split heads)
// LAYOUT 2: out16[((b*16+h)*64 + d)*NkT + s]     (transposed V, d-major)
// LAYOUT 3: outF[m*1024 + n]                     (final f32 output)
template<int LAYOUT>
__global__ __launch_bounds__(256, 2)
void gemm_bt(const u16* __restrict__ A, const u16* __restrict__ Bt,
             const float* __restrict__ bias, u16* __restrict__ out16,
             float* __restrict__ outF, int K, int logS, float scale, int NkT)
{
  __shared__ __align__(128) char Alds[16384];
  __shared__ __align__(128) char Blds[16384];
  const int tid = threadIdx.x, lane = tid & 63, w = tid >> 6;
  const int g = lane >> 4, lm = lane & 15;
  const int row0 = blockIdx.x * 128, col0 = blockIdx.y * 128;
  const int wr = (w >> 1) * 64, wc = (w & 1) * 64;

  f32x4 acc[4][4];
  #pragma unroll
  for (int i = 0; i < 4; ++i)
    #pragma unroll
    for (int j = 0; j < 4; ++j) acc[i][j] = {0.f, 0.f, 0.f, 0.f};

  const char* Ag = (const char*)A  + ((long)row0 * K) * 2;
  const char* Bg = (const char*)Bt + ((long)col0 * K) * 2;

  for (int k0 = 0; k0 < K; k0 += 64){
    stage_tile<128>(Ag + k0*2, (long)K*2, Alds, tid);
    stage_tile<128>(Bg + k0*2, (long)K*2, Blds, tid);
    __syncthreads();
    #pragma unroll
    for (int kk = 0; kk < 2; ++kk){
      half8 af[4], bfr[4];
      #pragma unroll
      for (int mi = 0; mi < 4; ++mi){
        int r = wr + mi*16 + lm;
        af[mi] = *(const half8*)(Alds + r*128 + ((kk*64 + g*16) ^ ((r & 7) << 4)));
      }
      #pragma unroll
      for (int ni = 0; ni < 4; ++ni){
        int r = wc + ni*16 + lm;
        bfr[ni] = *(const half8*)(Blds + r*128 + ((kk*64 + g*16) ^ ((r & 7) << 4)));
      }
      #pragma unroll
      for (int mi = 0; mi < 4; ++mi)
        #pragma unroll
        for (int ni = 0; ni < 4; ++ni)
          acc[mi][ni] = __builtin_amdgcn_mfma_f32_16x16x32_f16(af[mi], bfr[ni], acc[mi][ni], 0, 0, 0);
    }
    __syncthreads();
  }

  float bv[4];
  #pragma unroll
  for (int ni = 0; ni < 4; ++ni) bv[ni] = bias[col0 + wc + ni*16 + lm];
  #pragma unroll
  for (int mi = 0; mi < 4; ++mi){
    #pragma unroll
    for (int ni = 0; ni < 4; ++ni){
      int n = col0 + wc + ni*16 + lm;
      #pragma unroll
      for (int r = 0; r < 4; ++r){
        int m = row0 + wr + mi*16 + g*4 + r;
        float v = (acc[mi][ni][r] + bv[ni]) * scale;
        if (LAYOUT == 3){
          outF[(long)m * 1024 + n] = v;
        } else {
          int b_ = m >> logS, s_ = m & ((1 << logS) - 1);
          int h_ = n >> 6,    d_ = n & 63;
          long dst;
          if (LAYOUT == 1) dst = (((long)(b_*16 + h_) << logS) + s_) * 64 + d_;
          else             dst = ((long)(b_*16 + h_) * 64 + d_) * (long)NkT + s_;
          out16[dst] = f2h(v);
        }
      }
    }
  }
}

// Flash attention. Grid (8 qtiles, 64 bh), 256 threads. Each wave owns 32 q-rows
// (2 stripes of 16). Swapped QK^T: S^T = mfma(Kfrag, Qfrag) puts a full P-row
// slice in each lane (q = lane&15): softmax is 2 shfl_xor; P feeds the PV MFMA
// A-operand directly in registers. The k-permutation pi(g,i) used for P is the
// SAME one used to fetch V's B-frag, so the contraction is exact for any HW k-map.
__global__ __launch_bounds__(256, 2)
void attn_fused(const u16* __restrict__ Qw, const u16* __restrict__ Kw,
                const u16* __restrict__ Vtw, u16* __restrict__ AO)
{
  __shared__ __align__(128) char Klds[8192];   // 64 kpos x 64 d
  __shared__ __align__(128) char Vlds[8192];   // 64 d x 64 kpos (d-major)
  const int tid = threadIdx.x, lane = tid & 63, w = tid >> 6;
  const int g = lane >> 4, lm = lane & 15;
  const int qt = blockIdx.x, bh = blockIdx.y;
  const long qbase = (long)bh * 1024 * 64;
  const long kbase = (long)bh * 2048 * 64;
  const long vbase = (long)bh * 64 * 2048;

  const int q0[2] = { qt*128 + w*32, qt*128 + w*32 + 16 };
  half8 aQ[2][2];
  #pragma unroll
  for (int s = 0; s < 2; ++s)
    #pragma unroll
    for (int kk = 0; kk < 2; ++kk)
      aQ[s][kk] = *(const half8*)((const char*)Qw + (qbase + (long)(q0[s] + lm)*64 + kk*32 + g*8)*2);

  float mrun[2] = {-3e38f, -3e38f};
  float lrun[2] = {0.f, 0.f};
  f32x4 O[2][4];
  #pragma unroll
  for (int s = 0; s < 2; ++s)
    #pragma unroll
    for (int di = 0; di < 4; ++di) O[s][di] = {0.f, 0.f, 0.f, 0.f};

  for (int kt = 0; kt < 2048; kt += 64){
    stage_tile<64>((const char*)Kw  + (kbase + (long)kt*64)*2, 128,  Klds, tid);
    stage_tile<64>((const char*)Vtw + (vbase + kt)*2,          4096, Vlds, tid);
    __syncthreads();

    half8 kf[4][2];                      // shared by both stripes
    #pragma unroll
    for (int t = 0; t < 4; ++t)
      #pragma unroll
      for (int kk = 0; kk < 2; ++kk){
        int r = t*16 + lm;
        kf[t][kk] = *(const half8*)(Klds + r*128 + ((kk*64 + g*16) ^ ((r & 7) << 4)));
      }

    #pragma unroll
    for (int s = 0; s < 2; ++s){
      // S^T tiles: lane holds S[q=lm][kpos = kt + t*16 + g*4 + r]  (Q pre-scaled by 1/8)
      f32x4 sc[4];
      #pragma unroll
      for (int t = 0; t < 4; ++t){
        f32x4 z = {0.f, 0.f, 0.f, 0.f};
        z = __builtin_amdgcn_mfma_f32_16x16x32_f16(kf[t][0], aQ[s][0], z, 0, 0, 0);
        z = __builtin_amdgcn_mfma_f32_16x16x32_f16(kf[t][1], aQ[s][1], z, 0, 0, 0);
        sc[t] = z;
      }
      // online softmax for this lane's q
      float pm = sc[0][0];
      #pragma unroll
      for (int t = 0; t < 4; ++t)
        #pragma unroll
        for (int r = 0; r < 4; ++r) pm = fmaxf(pm, sc[t][r]);
      pm = fmaxf(pm, __shfl_xor(pm, 16));
      pm = fmaxf(pm, __shfl_xor(pm, 32));
      float mnew = fmaxf(mrun[s], pm);
      float fac  = __expf(mrun[s] - mnew);
      float ls = 0.f;
      #pragma unroll
      for (int t = 0; t < 4; ++t)
        #pragma unroll
        for (int r = 0; r < 4; ++r){ float p = __expf(sc[t][r] - mnew); sc[t][r] = p; ls += p; }
      ls += __shfl_xor(ls, 16);
      ls += __shfl_xor(ls, 32);
      lrun[s] = lrun[s]*fac + ls;
      mrun[s] = mnew;
      // rescale O: O-row (q-local) = g*4+r, its factor lives at lane (g<<4)|(g*4+r)
      float frow[4];
      #pragma unroll
      for (int r = 0; r < 4; ++r) frow[r] = __shfl(fac, (lane & 48) | (g*4 + r));
      #pragma unroll
      for (int di = 0; di < 4; ++di){
        O[s][di][0] *= frow[0]; O[s][di][1] *= frow[1];
        O[s][di][2] *= frow[2]; O[s][di][3] *= frow[3];
      }
      // pack P into PV A-frags: element i of half kh -> kpos-local kh*32 + (i>>2)*16 + g*4 + (i&3)
      half8 pa[2];
      #pragma unroll
      for (int kh = 0; kh < 2; ++kh)
        #pragma unroll
        for (int i = 0; i < 8; ++i){
          int t = kh*2 + (i >> 2), r = i & 3;
          pa[kh][i] = (_Float16)sc[t][r];
        }
      // PV: O[q][d] += P[q][kpos] * V[kpos][d]; V B-frag uses the SAME k-permutation
      #pragma unroll
      for (int di = 0; di < 4; ++di){
        int d = di*16 + lm;
        int swz = (d & 7) << 4;
        #pragma unroll
        for (int kh = 0; kh < 2; ++kh){
          half4 lo = *(const half4*)(Vlds + d*128 + ((kh*64 + g*8)      ^ swz));
          half4 hi = *(const half4*)(Vlds + d*128 + ((kh*64 + g*8 + 32) ^ swz));
          half8 vf = { lo[0], lo[1], lo[2], lo[3], hi[0], hi[1], hi[2], hi[3] };
          O[s][di] = __builtin_amdgcn_mfma_f32_16x16x32_f16(pa[kh], vf, O[s][di], 0, 0, 0);
        }
      }
    }
    __syncthreads();
  }

  const int b = bh >> 4, h = bh & 15;
  #pragma unroll
  for (int s = 0; s < 2; ++s){
    float inv = 1.f / lrun[s];
    float irow[4];
    #pragma unroll
    for (int r = 0; r < 4; ++r) irow[r] = __shfl(inv, (lane & 48) | (g*4 + r));
    #pragma unroll
    for (int di = 0; di < 4; ++di)
      #pragma unroll
      for (int r = 0; r < 4; ++r){
        long q = q0[s] + g*4 + r;
        AO[((long)b*1024 + q)*1024 + h*64 + di*16 + lm] = f2h(O[s][di][r] * irow[r]);
      }
  }
}

extern "C" void kernel_launch(void* const* d_in, const int* in_sizes, int n_in,
                              void* d_out, int out_size, void* d_ws, size_t ws_size,
                              hipStream_t stream)
{
  const float* query = (const float*)d_in[0];
  const float* key   = (const float*)d_in[1];
  const float* value = (const float*)d_in[2];
  const float* Wq = (const float*)d_in[3];
  const float* bq = (const float*)d_in[4];
  const float* Wk = (const float*)d_in[5];
  const float* bk = (const float*)d_in[6];
  const float* Wv = (const float*)d_in[7];
  const float* bv = (const float*)d_in[8];
  const float* Wo = (const float*)d_in[9];
  const float* bo = (const float*)d_in[10];
  float* out = (float*)d_out;

  char* p = (char*)d_ws;
  auto alloc = [&](long bytes){ char* r = p; p += bytes; return r; };
  u16* qH  = (u16*)alloc( 8l<<20);   // [4096][1024] fp16
  u16* kH  = (u16*)alloc(12l<<20);   // [8192][768]
  u16* vH  = (u16*)alloc(12l<<20);   // [8192][768]
  u16* WqH = (u16*)alloc( 2l<<20);   // [1024][1024]
  u16* WkH = (u16*)alloc( 2l<<20);   // [1024][768]
  u16* WvH = (u16*)alloc( 2l<<20);   // [1024][768]
  u16* WoH = (u16*)alloc( 2l<<20);   // [1024][1024]
  u16* Qw  = (u16*)alloc( 8l<<20);   // [64][1024][64]
  u16* Kw  = (u16*)alloc(16l<<20);   // [64][2048][64]
  u16* Vtw = (u16*)alloc(16l<<20);   // [64][64][2048]
  u16* AO  = (u16*)alloc( 8l<<20);   // [4096][1024]

  Cvt7 ca;
  ca.seg[0] = { query, qH,  4096*1024/4 };
  ca.seg[1] = { key,   kH,  8192*768/4  };
  ca.seg[2] = { value, vH,  8192*768/4  };
  ca.seg[3] = { Wq,    WqH, 1024*1024/4 };
  ca.seg[4] = { Wk,    WkH, 1024*768/4  };
  ca.seg[5] = { Wv,    WvH, 1024*768/4  };
  ca.seg[6] = { Wo,    WoH, 1024*1024/4 };
  cvt_f32_f16<<<dim3(512, 7), 256, 0, stream>>>(ca);

  dim3 blk(256);
  // Q pre-scaled by 1/sqrt(64)=0.125 (exact power of 2 in fp16)
  gemm_bt<1><<<dim3(32, 8), blk, 0, stream>>>(qH, WqH, bq, Qw,  nullptr, 1024, 10, 0.125f, 2048);
  gemm_bt<1><<<dim3(64, 8), blk, 0, stream>>>(kH, WkH, bk, Kw,  nullptr,  768, 11, 1.0f,   2048);
  gemm_bt<2><<<dim3(64, 8), blk, 0, stream>>>(vH, WvH, bv, Vtw, nullptr,  768, 11, 1.0f,   2048);
  attn_fused<<<dim3(8, 64), blk, 0, stream>>>(Qw, Kw, Vtw, AO);
  gemm_bt<3><<<dim3(32, 8), blk, 0, stream>>>(AO, WoH, bo, nullptr, out, 1024, 10, 1.0f, 2048);
}

// Round 3
// 267.563 us; speedup vs baseline: 1.0415x; 1.0415x over previous
//
#include <hip/hip_runtime.h>
#include <stdint.h>

// MultiHeadCrossAttention: B=4, Nq=1024, Nk=2048, QUERY_DIM=1024, KEY_DIM=768, H=16, D=64
// Inputs/outputs FLOAT32. Internally fp16 MFMA with f32 accumulate:
//   0) cvt: f32 -> fp16 copies of query/key/value/Wq/Wk/Wv/Wo in ws
//   1) fused QKV projection (one launch, 2560 blocks, BM=64 BN=128):
//        Q = (query@Wq^T+bq)*0.125 -> [bh][1024][64]   (split heads)
//        K =  key @Wk^T+bk         -> [bh][2048][64]
//        V = value@Wv^T+bv         -> [bh][64][2048]   (d-major, via LDS-transpose epilogue)
//   2) flash attention (512 blocks x 8 waves, XCD-grouped bh mapping) -> fp16 [4096][1024]
//   3) out = AO @ Wo^T + bo -> d_out (f32), BM=64, 512 blocks

typedef __attribute__((ext_vector_type(4))) float f32x4;
typedef __attribute__((ext_vector_type(8))) _Float16 half8;
typedef __attribute__((ext_vector_type(4))) _Float16 half4;
typedef __attribute__((ext_vector_type(4))) short short4v;
typedef __attribute__((ext_vector_type(8))) short short8;
typedef unsigned short u16;

__device__ __forceinline__ u16 f2h(float f){
  _Float16 h = (_Float16)f;
  return __builtin_bit_cast(unsigned short, h);
}

__device__ __forceinline__ void gload16(const void* g, void* lds){
  __builtin_amdgcn_global_load_lds((const __attribute__((address_space(1))) void*)g,
                                   (__attribute__((address_space(3))) void*)lds, 16, 0, 0);
}

// ---------- f32 -> fp16 pre-convert ----------
struct Seg { const float* s; u16* d; int n4; };
struct Cvt7 { Seg seg[7]; };

__global__ __launch_bounds__(256) void cvt_f32_f16(Cvt7 a){
  Seg sg = a.seg[blockIdx.y];
  const long stride = (long)gridDim.x * 256;
  for (long i = (long)blockIdx.x*256 + threadIdx.x; i < sg.n4; i += stride){
    f32x4 v = *(const f32x4*)(sg.s + i*4);
    short4v h;
    h[0] = (short)f2h(v[0]); h[1] = (short)f2h(v[1]);
    h[2] = (short)f2h(v[2]); h[3] = (short)f2h(v[3]);
    *(short4v*)(sg.d + i*4) = h;
  }
}

// Stage R rows x 128B (64 fp16/row) global->LDS, 16B-chunk XOR swizzle.
// LDS slot (r,b) holds global byte (r, b ^ ((r&7)<<4)); readers apply the same XOR.
// LDS dest base is wave-uniform (global_load_lds semantics); permutation applied
// on the per-lane GLOBAL source address (guide rule #21).
template<int R, int THREADS>
__device__ __forceinline__ void stage_tile(const char* gbase, long gstride, char* lds, int tid){
  const int w = tid >> 6, lane = tid & 63;
  #pragma unroll
  for (int it = 0; it < R*8/THREADS; ++it){
    int c  = it*THREADS + w*64 + lane;       // 16B chunk id
    int r  = c >> 3;                         // row (8 chunks/row)
    int bs = (c & 7) << 4;
    int sb = bs ^ ((r & 7) << 4);            // inverse-swizzled source byte
    gload16(gbase + (long)r*gstride + sb, lds + (it*THREADS + w*64)*16);
  }
}

// Shared 64x128 GEMM mainloop: C = A @ Bt^T, BK=64, 4 waves (2x2), 16x16x32 f16 MFMA.
// Wave tile 32x64; acc[mi<2][ni<4]; frag coords: m = row0+wr+mi*16+g*4+r, n = col0+wc+ni*16+lm.
__device__ __forceinline__ void gemm64_mainloop(const u16* A, const u16* Bt, int K,
                                                int row0, int col0, int tid,
                                                char* Alds, char* Blds, f32x4 acc[2][4]){
  const int lane = tid & 63, w = tid >> 6;
  const int g = lane >> 4, lm = lane & 15;
  const int wr = (w >> 1) * 32, wc = (w & 1) * 64;
  const char* Ag = (const char*)A  + ((long)row0 * K) * 2;
  const char* Bg = (const char*)Bt + ((long)col0 * K) * 2;
  for (int k0 = 0; k0 < K; k0 += 64){
    stage_tile<64, 256>(Ag + k0*2, (long)K*2, Alds, tid);
    stage_tile<128, 256>(Bg + k0*2, (long)K*2, Blds, tid);
    __syncthreads();
    #pragma unroll
    for (int kk = 0; kk < 2; ++kk){
      half8 af[2], bfr[4];
      #pragma unroll
      for (int mi = 0; mi < 2; ++mi){
        int r = wr + mi*16 + lm;
        af[mi] = *(const half8*)(Alds + r*128 + ((kk*64 + g*16) ^ ((r & 7) << 4)));
      }
      #pragma unroll
      for (int ni = 0; ni < 4; ++ni){
        int r = wc + ni*16 + lm;
        bfr[ni] = *(const half8*)(Blds + r*128 + ((kk*64 + g*16) ^ ((r & 7) << 4)));
      }
      #pragma unroll
      for (int mi = 0; mi < 2; ++mi)
        #pragma unroll
        for (int ni = 0; ni < 4; ++ni)
          acc[mi][ni] = __builtin_amdgcn_mfma_f32_16x16x32_f16(af[mi], bfr[ni], acc[mi][ni], 0, 0, 0);
    }
    __syncthreads();
  }
}

// Fused Q/K/V projections. blocks: [0,512) Q, [512,1536) K, [1536,2560) V.
__global__ __launch_bounds__(256, 4)
void qkv_proj(const u16* __restrict__ qH, const u16* __restrict__ kH, const u16* __restrict__ vH,
              const u16* __restrict__ WqH, const u16* __restrict__ WkH, const u16* __restrict__ WvH,
              const float* __restrict__ bq, const float* __restrict__ bk, const float* __restrict__ bv,
              u16* __restrict__ Qw, u16* __restrict__ Kw, u16* __restrict__ Vtw)
{
  __shared__ __align__(128) char Alds[8192];
  __shared__ __align__(128) char Blds[16384];
  const int tid = threadIdx.x, lane = tid & 63, w = tid >> 6;
  const int g = lane >> 4, lm = lane & 15;

  int bid = blockIdx.x;
  const u16 *A, *Bt; const float* bias; u16* out16;
  int K, logS, local; float scale = 1.0f;
  int which;
  if (bid < 512)       { which = 0; local = bid;        A = qH; Bt = WqH; bias = bq; out16 = Qw;  K = 1024; logS = 10; scale = 0.125f; }
  else if (bid < 1536) { which = 1; local = bid - 512;  A = kH; Bt = WkH; bias = bk; out16 = Kw;  K = 768;  logS = 11; }
  else                 { which = 2; local = bid - 1536; A = vH; Bt = WvH; bias = bv; out16 = Vtw; K = 768;  logS = 11; }
  const int rb = local >> 3, cb = local & 7;
  const int row0 = rb * 64, col0 = cb * 128;

  f32x4 acc[2][4];
  #pragma unroll
  for (int i = 0; i < 2; ++i)
    #pragma unroll
    for (int j = 0; j < 4; ++j) acc[i][j] = {0.f, 0.f, 0.f, 0.f};

  gemm64_mainloop(A, Bt, K, row0, col0, tid, Alds, Blds, acc);

  const int wr = (w >> 1) * 32, wc = (w & 1) * 64;
  if (which != 2){
    // split-head scalar epilogue: dst[((b*16+h)<<logS | s)*64 + d]
    #pragma unroll
    for (int mi = 0; mi < 2; ++mi)
      #pragma unroll
      for (int ni = 0; ni < 4; ++ni){
        int n = col0 + wc + ni*16 + lm;
        float bvv = bias[n];
        int h_ = n >> 6, d_ = n & 63;
        #pragma unroll
        for (int r = 0; r < 4; ++r){
          int m = row0 + wr + mi*16 + g*4 + r;
          int b_ = m >> logS, s_ = m & ((1 << logS) - 1);
          long dst = (((long)(b_*16 + h_) << logS) + s_) * 64 + d_;
          out16[dst] = f2h((acc[mi][ni][r] + bvv) * scale);
        }
      }
  } else {
    // V: transpose 64x128 tile through LDS (reuse Blds), then 16B-coalesced
    // stores of V^T[(b*16+h)*64 + d][s].  TB[n'][m'] fp16, 128B rows, XOR-16B swizzle.
    #pragma unroll
    for (int mi = 0; mi < 2; ++mi)
      #pragma unroll
      for (int ni = 0; ni < 4; ++ni){
        int np = wc + ni*16 + lm;
        float bvv = bias[col0 + np];
        short4v h4;
        #pragma unroll
        for (int r = 0; r < 4; ++r) h4[r] = (short)f2h(acc[mi][ni][r] + bvv);
        int mb = (wr + mi*16 + g*4) * 2;
        *(short4v*)(Blds + np*128 + (mb ^ ((np & 7) << 4))) = h4;
      }
    __syncthreads();
    const int b_ = row0 >> 11;
    #pragma unroll
    for (int pass = 0; pass < 4; ++pass){
      int idx = pass*256 + tid, row = idx >> 3, c = idx & 7;
      short8 v = *(const short8*)(Blds + row*128 + ((c*16) ^ ((row & 7) << 4)));
      int ng = col0 + row, h_ = ng >> 6, d_ = ng & 63;
      long dst = ((long)(b_*16 + h_)*64 + d_)*2048 + (row0 & 2047) + c*8;
      *(short8*)(out16 + dst) = v;
    }
  }
}

// Flash attention: 512 blocks x 512 threads (8 waves x 16 q-rows = 128-q tile).
// Block->(bh,qt) mapping groups all 8 q-tiles of one bh on one XCD (p%8 heuristic)
// so K/V (512KB/bh, 8 bh = 4MB) stay L2-resident. Swapped QK^T: lane holds a full
// P-row slice (q = lane&15); softmax = 2 shfl_xor; P feeds PV A-operand in regs,
// V B-frag fetched with the SAME k-permutation pi(g,i), so contraction is exact.
__global__ __launch_bounds__(512, 4)
void attn_fused(const u16* __restrict__ Qw, const u16* __restrict__ Kw,
                const u16* __restrict__ Vtw, u16* __restrict__ AO)
{
  __shared__ __align__(128) char Klds[8192];   // 64 kpos x 64 d
  __shared__ __align__(128) char Vlds[8192];   // 64 d x 64 kpos (d-major)
  const int tid = threadIdx.x, lane = tid & 63, w = tid >> 6;
  const int g = lane >> 4, lm = lane & 15;
  const int p = blockIdx.x;
  const int slot = p >> 3;
  const int bh = (p & 7) + ((slot & 7) << 3);
  const int qt = slot >> 3;
  const long qbase = (long)bh * 1024 * 64;
  const long kbase = (long)bh * 2048 * 64;
  const long vbase = (long)bh * 64 * 2048;

  const int q0 = qt*128 + w*16;
  half8 aQ[2];
  #pragma unroll
  for (int kk = 0; kk < 2; ++kk)
    aQ[kk] = *(const half8*)((const char*)Qw + (qbase + (long)(q0 + lm)*64 + kk*32 + g*8)*2);

  float mrun = -3e38f, lrun = 0.f;
  f32x4 O[4];
  #pragma unroll
  for (int di = 0; di < 4; ++di) O[di] = {0.f, 0.f, 0.f, 0.f};

  for (int kt = 0; kt < 2048; kt += 64){
    stage_tile<64, 512>((const char*)Kw  + (kbase + (long)kt*64)*2, 128,  Klds, tid);
    stage_tile<64, 512>((const char*)Vtw + (vbase + kt)*2,          4096, Vlds, tid);
    __syncthreads();

    half8 kf[4][2];
    #pragma unroll
    for (int t = 0; t < 4; ++t)
      #pragma unroll
      for (int kk = 0; kk < 2; ++kk){
        int r = t*16 + lm;
        kf[t][kk] = *(const half8*)(Klds + r*128 + ((kk*64 + g*16) ^ ((r & 7) << 4)));
      }

    // S^T tiles: lane holds S[q=lm][kpos = kt + t*16 + g*4 + r]  (Q pre-scaled 1/8)
    f32x4 sc[4];
    #pragma unroll
    for (int t = 0; t < 4; ++t){
      f32x4 z = {0.f, 0.f, 0.f, 0.f};
      z = __builtin_amdgcn_mfma_f32_16x16x32_f16(kf[t][0], aQ[0], z, 0, 0, 0);
      z = __builtin_amdgcn_mfma_f32_16x16x32_f16(kf[t][1], aQ[1], z, 0, 0, 0);
      sc[t] = z;
    }
    // online softmax
    float pm = sc[0][0];
    #pragma unroll
    for (int t = 0; t < 4; ++t)
      #pragma unroll
      for (int r = 0; r < 4; ++r) pm = fmaxf(pm, sc[t][r]);
    pm = fmaxf(pm, __shfl_xor(pm, 16));
    pm = fmaxf(pm, __shfl_xor(pm, 32));
    float mnew = fmaxf(mrun, pm);
    float fac  = __expf(mrun - mnew);
    float ls = 0.f;
    #pragma unroll
    for (int t = 0; t < 4; ++t)
      #pragma unroll
      for (int r = 0; r < 4; ++r){ float pv = __expf(sc[t][r] - mnew); sc[t][r] = pv; ls += pv; }
    ls += __shfl_xor(ls, 16);
    ls += __shfl_xor(ls, 32);
    lrun = lrun*fac + ls;
    mrun = mnew;
    float frow[4];
    #pragma unroll
    for (int r = 0; r < 4; ++r) frow[r] = __shfl(fac, (lane & 48) | (g*4 + r));
    #pragma unroll
    for (int di = 0; di < 4; ++di){
      O[di][0] *= frow[0]; O[di][1] *= frow[1];
      O[di][2] *= frow[2]; O[di][3] *= frow[3];
    }
    // pack P: element i of half kh -> kpos-local kh*32 + (i>>2)*16 + g*4 + (i&3)
    half8 pa[2];
    #pragma unroll
    for (int kh = 0; kh < 2; ++kh)
      #pragma unroll
      for (int i = 0; i < 8; ++i){
        int t = kh*2 + (i >> 2), r = i & 3;
        pa[kh][i] = (_Float16)sc[t][r];
      }
    // PV: O[q][d] += P[q][kpos] * V[kpos][d]
    #pragma unroll
    for (int di = 0; di < 4; ++di){
      int d = di*16 + lm;
      int swz = (d & 7) << 4;
      #pragma unroll
      for (int kh = 0; kh < 2; ++kh){
        half4 lo = *(const half4*)(Vlds + d*128 + ((kh*64 + g*8)      ^ swz));
        half4 hi = *(const half4*)(Vlds + d*128 + ((kh*64 + g*8 + 32) ^ swz));
        half8 vf = { lo[0], lo[1], lo[2], lo[3], hi[0], hi[1], hi[2], hi[3] };
        O[di] = __builtin_amdgcn_mfma_f32_16x16x32_f16(pa[kh], vf, O[di], 0, 0, 0);
      }
    }
    __syncthreads();
  }

  const int b = bh >> 4, h = bh & 15;
  float inv = 1.f / lrun;
  float irow[4];
  #pragma unroll
  for (int r = 0; r < 4; ++r) irow[r] = __shfl(inv, (lane & 48) | (g*4 + r));
  #pragma unroll
  for (int di = 0; di < 4; ++di)
    #pragma unroll
    for (int r = 0; r < 4; ++r){
      long q = q0 + g*4 + r;
      AO[((long)b*1024 + q)*1024 + h*64 + di*16 + lm] = f2h(O[di][r] * irow[r]);
    }
}

// O-projection: out = AO @ Wo^T + bo, f32 output. 512 blocks.
__global__ __launch_bounds__(256, 4)
void gemm_o(const u16* __restrict__ A, const u16* __restrict__ Bt,
            const float* __restrict__ bias, float* __restrict__ outF)
{
  __shared__ __align__(128) char Alds[8192];
  __shared__ __align__(128) char Blds[16384];
  const int tid = threadIdx.x, lane = tid & 63, w = tid >> 6;
  const int g = lane >> 4, lm = lane & 15;
  const int rb = blockIdx.x >> 3, cb = blockIdx.x & 7;
  const int row0 = rb * 64, col0 = cb * 128;

  f32x4 acc[2][4];
  #pragma unroll
  for (int i = 0; i < 2; ++i)
    #pragma unroll
    for (int j = 0; j < 4; ++j) acc[i][j] = {0.f, 0.f, 0.f, 0.f};

  gemm64_mainloop(A, Bt, 1024, row0, col0, tid, Alds, Blds, acc);

  const int wr = (w >> 1) * 32, wc = (w & 1) * 64;
  #pragma unroll
  for (int mi = 0; mi < 2; ++mi)
    #pragma unroll
    for (int ni = 0; ni < 4; ++ni){
      int n = col0 + wc + ni*16 + lm;
      float bvv = bias[n];
      #pragma unroll
      for (int r = 0; r < 4; ++r){
        int m = row0 + wr + mi*16 + g*4 + r;
        outF[(long)m * 1024 + n] = acc[mi][ni][r] + bvv;
      }
    }
}

extern "C" void kernel_launch(void* const* d_in, const int* in_sizes, int n_in,
                              void* d_out, int out_size, void* d_ws, size_t ws_size,
                              hipStream_t stream)
{
  const float* query = (const float*)d_in[0];
  const float* key   = (const float*)d_in[1];
  const float* value = (const float*)d_in[2];
  const float* Wq = (const float*)d_in[3];
  const float* bq = (const float*)d_in[4];
  const float* Wk = (const float*)d_in[5];
  const float* bk = (const float*)d_in[6];
  const float* Wv = (const float*)d_in[7];
  const float* bv = (const float*)d_in[8];
  const float* Wo = (const float*)d_in[9];
  const float* bo = (const float*)d_in[10];
  float* out = (float*)d_out;

  char* p = (char*)d_ws;
  auto alloc = [&](long bytes){ char* r = p; p += bytes; return r; };
  u16* qH  = (u16*)alloc( 8l<<20);   // [4096][1024] fp16
  u16* kH  = (u16*)alloc(12l<<20);   // [8192][768]
  u16* vH  = (u16*)alloc(12l<<20);   // [8192][768]
  u16* WqH = (u16*)alloc( 2l<<20);   // [1024][1024]
  u16* WkH = (u16*)alloc( 2l<<20);   // [1024][768]
  u16* WvH = (u16*)alloc( 2l<<20);   // [1024][768]
  u16* WoH = (u16*)alloc( 2l<<20);   // [1024][1024]
  u16* Qw  = (u16*)alloc( 8l<<20);   // [64][1024][64]
  u16* Kw  = (u16*)alloc(16l<<20);   // [64][2048][64]
  u16* Vtw = (u16*)alloc(16l<<20);   // [64][64][2048]
  u16* AO  = (u16*)alloc( 8l<<20);   // [4096][1024]

  Cvt7 ca;
  ca.seg[0] = { query, qH,  4096*1024/4 };
  ca.seg[1] = { key,   kH,  8192*768/4  };
  ca.seg[2] = { value, vH,  8192*768/4  };
  ca.seg[3] = { Wq,    WqH, 1024*1024/4 };
  ca.seg[4] = { Wk,    WkH, 1024*768/4  };
  ca.seg[5] = { Wv,    WvH, 1024*768/4  };
  ca.seg[6] = { Wo,    WoH, 1024*1024/4 };
  cvt_f32_f16<<<dim3(512, 7), 256, 0, stream>>>(ca);

  qkv_proj<<<dim3(2560), dim3(256), 0, stream>>>(qH, kH, vH, WqH, WkH, WvH,
                                                 bq, bk, bv, Qw, Kw, Vtw);
  attn_fused<<<dim3(512), dim3(512), 0, stream>>>(Qw, Kw, Vtw, AO);
  gemm_o<<<dim3(512), dim3(256), 0, stream>>>(AO, WoH, bo, out);
}

// Round 5
// 256.693 us; speedup vs baseline: 1.0856x; 1.0423x over previous
//
#include <hip/hip_runtime.h>
#include <stdint.h>

// MultiHeadCrossAttention: B=4, Nq=1024, Nk=2048, QUERY_DIM=1024, KEY_DIM=768, H=16, D=64
// Inputs/outputs FLOAT32. Internally fp16 MFMA with f32 accumulate:
//   0) cvt: f32 -> fp16 copies of query/key/value/Wq/Wk/Wv/Wo in ws
//   1) fused QKV projection (2560 blocks, BM=64 BN=128, 2-phase counted-vmcnt pipeline)
//   2) flash attention (512 blocks x 8 waves, XCD-grouped bh, 2-phase pipeline, defer-max)
//   3) out = AO @ Wo^T + bo (f32)

typedef __attribute__((ext_vector_type(4))) float f32x4;
typedef __attribute__((ext_vector_type(8))) _Float16 half8;
typedef __attribute__((ext_vector_type(4))) _Float16 half4;
typedef __attribute__((ext_vector_type(2))) _Float16 half2v;
typedef __attribute__((ext_vector_type(4))) short short4v;
typedef __attribute__((ext_vector_type(8))) short short8;
typedef unsigned short u16;

__device__ __forceinline__ u16 f2h(float f){
  _Float16 h = (_Float16)f;
  return __builtin_bit_cast(unsigned short, h);
}

__device__ __forceinline__ void gload16(const void* g, void* lds){
  __builtin_amdgcn_global_load_lds((const __attribute__((address_space(1))) void*)g,
                                   (__attribute__((address_space(3))) void*)lds, 16, 0, 0);
}

// ---------- f32 -> fp16 pre-convert ----------
struct Seg { const float* s; u16* d; int n4; };
struct Cvt7 { Seg seg[7]; };

__global__ __launch_bounds__(256) void cvt_f32_f16(Cvt7 a){
  Seg sg = a.seg[blockIdx.y];
  const long stride = (long)gridDim.x * 256;
  for (long i = (long)blockIdx.x*256 + threadIdx.x; i < sg.n4; i += stride){
    f32x4 v = *(const f32x4*)(sg.s + i*4);
    short4v h;
    h[0] = (short)f2h(v[0]); h[1] = (short)f2h(v[1]);
    h[2] = (short)f2h(v[2]); h[3] = (short)f2h(v[3]);
    *(short4v*)(sg.d + i*4) = h;
  }
}

// Stage R rows x 128B (64 fp16/row) global->LDS, 16B-chunk XOR swizzle.
// LDS slot (r,b) holds global byte (r, b ^ ((r&7)<<4)); readers apply the same XOR.
// LDS dest base is wave-uniform (global_load_lds adds lane*16); the permutation is
// applied on the per-lane GLOBAL source address (guide rule #21).
template<int R, int THREADS>
__device__ __forceinline__ void stage_tile(const char* gbase, long gstride, char* lds, int tid){
  const int w = tid >> 6, lane = tid & 63;
  #pragma unroll
  for (int it = 0; it < R*8/THREADS; ++it){
    int c  = it*THREADS + w*64 + lane;       // 16B chunk id
    int r  = c >> 3;                         // row (8 chunks/row)
    int bs = (c & 7) << 4;
    int sb = bs ^ ((r & 7) << 4);            // inverse-swizzled source byte
    gload16(gbase + (long)r*gstride + sb, lds + (it*THREADS + w*64)*16);
  }
}

// 64x128 GEMM mainloop, double-buffered, counted vmcnt (T3/T4 minimum-2-phase):
// issue stage(t+1) -> s_waitcnt vmcnt(6) [tile t landed; t+1 stays in flight]
// -> s_barrier -> compute(t) -> s_barrier.  BK=64, 4 waves (2x2), 16x16x32 f16 MFMA.
// lds layout: [sel*24576 + {A:8192 | B:16384}], total 48 KiB.
__device__ __forceinline__ void gemm64_pipe(const u16* A, const u16* Bt, int K,
                                            int row0, int col0, int tid,
                                            char* lds, f32x4 acc[2][4]){
  const int lane = tid & 63, w = tid >> 6;
  const int g = lane >> 4, lm = lane & 15;
  const int wr = (w >> 1) * 32, wc = (w & 1) * 64;
  const char* Ag = (const char*)A  + ((long)row0 * K) * 2;
  const char* Bg = (const char*)Bt + ((long)col0 * K) * 2;

  stage_tile<64, 256>(Ag, (long)K*2, lds, tid);
  stage_tile<128, 256>(Bg, (long)K*2, lds + 8192, tid);

  for (int k0 = 0; k0 < K; k0 += 64){
    char* cur = lds + ((k0 >> 6) & 1) * 24576;
    if (k0 + 64 < K){
      char* nxt = lds + ((((k0 >> 6) & 1) ^ 1)) * 24576;
      stage_tile<64, 256>(Ag + (long)(k0+64)*2, (long)K*2, nxt, tid);
      stage_tile<128, 256>(Bg + (long)(k0+64)*2, (long)K*2, nxt + 8192, tid);
      asm volatile("s_waitcnt vmcnt(6)" ::: "memory");
    } else {
      asm volatile("s_waitcnt vmcnt(0)" ::: "memory");
    }
    __builtin_amdgcn_s_barrier();
    char* Al = cur, *Bl = cur + 8192;
    #pragma unroll
    for (int kk = 0; kk < 2; ++kk){
      half8 af[2], bfr[4];
      #pragma unroll
      for (int mi = 0; mi < 2; ++mi){
        int r = wr + mi*16 + lm;
        af[mi] = *(const half8*)(Al + r*128 + ((kk*64 + g*16) ^ ((r & 7) << 4)));
      }
      #pragma unroll
      for (int ni = 0; ni < 4; ++ni){
        int r = wc + ni*16 + lm;
        bfr[ni] = *(const half8*)(Bl + r*128 + ((kk*64 + g*16) ^ ((r & 7) << 4)));
      }
      #pragma unroll
      for (int mi = 0; mi < 2; ++mi)
        #pragma unroll
        for (int ni = 0; ni < 4; ++ni)
          acc[mi][ni] = __builtin_amdgcn_mfma_f32_16x16x32_f16(af[mi], bfr[ni], acc[mi][ni], 0, 0, 0);
    }
    __builtin_amdgcn_s_barrier();
  }
}

// Fused Q/K/V projections. work: [0,512) Q, [512,1536) K, [1536,2560) V.
// Chunked XCD map: xcd p%8 gets contiguous work range -> the 8 col-blocks sharing
// an A-row-panel land on one XCD (A fetched once, L2-reused across cb).
__global__ __launch_bounds__(256, 3)
void qkv_proj(const u16* __restrict__ qH, const u16* __restrict__ kH, const u16* __restrict__ vH,
              const u16* __restrict__ WqH, const u16* __restrict__ WkH, const u16* __restrict__ WvH,
              const float* __restrict__ bq, const float* __restrict__ bk, const float* __restrict__ bv,
              u16* __restrict__ Qw, u16* __restrict__ Kw, u16* __restrict__ Vtw)
{
  __shared__ __align__(128) char lds[49152];
  const int tid = threadIdx.x, lane = tid & 63, w = tid >> 6;
  const int g = lane >> 4, lm = lane & 15;

  int bid = (blockIdx.x & 7) * 320 + (blockIdx.x >> 3);   // 2560 = 8 * 320
  const u16 *A, *Bt; const float* bias; u16* out16;
  int K, logS, local; float scale = 1.0f;
  int which;
  if (bid < 512)       { which = 0; local = bid;        A = qH; Bt = WqH; bias = bq; out16 = Qw;  K = 1024; logS = 10; scale = 0.125f; }
  else if (bid < 1536) { which = 1; local = bid - 512;  A = kH; Bt = WkH; bias = bk; out16 = Kw;  K = 768;  logS = 11; }
  else                 { which = 2; local = bid - 1536; A = vH; Bt = WvH; bias = bv; out16 = Vtw; K = 768;  logS = 11; }
  const int rb = local >> 3, cb = local & 7;
  const int row0 = rb * 64, col0 = cb * 128;

  f32x4 acc[2][4];
  #pragma unroll
  for (int i = 0; i < 2; ++i)
    #pragma unroll
    for (int j = 0; j < 4; ++j) acc[i][j] = {0.f, 0.f, 0.f, 0.f};

  gemm64_pipe(A, Bt, K, row0, col0, tid, lds, acc);

  const int wr = (w >> 1) * 32, wc = (w & 1) * 64;
  if (which != 2){
    // split-head epilogue: dst[((b*16+h)<<logS | s)*64 + d]
    #pragma unroll
    for (int mi = 0; mi < 2; ++mi)
      #pragma unroll
      for (int ni = 0; ni < 4; ++ni){
        int n = col0 + wc + ni*16 + lm;
        float bvv = bias[n];
        int h_ = n >> 6, d_ = n & 63;
        #pragma unroll
        for (int r = 0; r < 4; ++r){
          int m = row0 + wr + mi*16 + g*4 + r;
          int b_ = m >> logS, s_ = m & ((1 << logS) - 1);
          long dst = (((long)(b_*16 + h_) << logS) + s_) * 64 + d_;
          out16[dst] = f2h((acc[mi][ni][r] + bvv) * scale);
        }
      }
  } else {
    // V: transpose 64x128 tile through LDS scratch, then 16B-coalesced stores
    // of V^T[(b*16+h)*64 + d][s].  scratch rows 128B, XOR-16B swizzle.
    #pragma unroll
    for (int mi = 0; mi < 2; ++mi)
      #pragma unroll
      for (int ni = 0; ni < 4; ++ni){
        int np = wc + ni*16 + lm;
        float bvv = bias[col0 + np];
        short4v h4;
        #pragma unroll
        for (int r = 0; r < 4; ++r) h4[r] = (short)f2h(acc[mi][ni][r] + bvv);
        int mb = (wr + mi*16 + g*4) * 2;
        *(short4v*)(lds + np*128 + (mb ^ ((np & 7) << 4))) = h4;
      }
    __syncthreads();
    const int b_ = row0 >> 11;
    #pragma unroll
    for (int pass = 0; pass < 4; ++pass){
      int idx = pass*256 + tid, row = idx >> 3, c = idx & 7;
      short8 v = *(const short8*)(lds + row*128 + ((c*16) ^ ((row & 7) << 4)));
      int ng = col0 + row, h_ = ng >> 6, d_ = ng & 63;
      long dst = ((long)(b_*16 + h_)*64 + d_)*2048 + (row0 & 2047) + c*8;
      *(short8*)(out16 + dst) = v;
    }
  }
}

// Flash attention: 512 blocks x 512 threads (8 waves x 16 q-rows). XCD-grouped bh.
// Double-buffered K/V staging with counted vmcnt(2). Swapped QK^T: lane holds a
// full P-row slice (q = lane&15); softmax = 2 shfl_xor; P feeds PV A-operand in
// regs with the SAME k-permutation pi(g,i) used for V's B-frag. Defer-max (T13).
__global__ __launch_bounds__(512, 4)
void attn_fused(const u16* __restrict__ Qw, const u16* __restrict__ Kw,
                const u16* __restrict__ Vtw, u16* __restrict__ AO)
{
  __shared__ __align__(128) char lds[32768];   // 2 x {K 8K | V 8K}
  const int tid = threadIdx.x, lane = tid & 63, w = tid >> 6;
  const int g = lane >> 4, lm = lane & 15;
  const int p = blockIdx.x;
  const int slot = p >> 3;
  const int bh = (p & 7) + ((slot & 7) << 3);
  const int qt = slot >> 3;
  const long qbase = (long)bh * 1024 * 64;
  const long kbase = (long)bh * 2048 * 64;
  const long vbase = (long)bh * 64 * 2048;

  const int q0 = qt*128 + w*16;
  half8 aQ[2];
  #pragma unroll
  for (int kk = 0; kk < 2; ++kk)
    aQ[kk] = *(const half8*)((const char*)Qw + (qbase + (long)(q0 + lm)*64 + kk*32 + g*8)*2);

  float mrun = -3e38f, lrun = 0.f;
  f32x4 O[4];
  #pragma unroll
  for (int di = 0; di < 4; ++di) O[di] = {0.f, 0.f, 0.f, 0.f};

  // prologue: stage tile 0 into buf0
  stage_tile<64, 512>((const char*)Kw  + kbase*2, 128,  lds, tid);
  stage_tile<64, 512>((const char*)Vtw + vbase*2, 4096, lds + 8192, tid);

  for (int kt = 0; kt < 2048; kt += 64){
    char* cur = lds + ((kt >> 6) & 1) * 16384;
    if (kt + 64 < 2048){
      char* nxt = lds + ((((kt >> 6) & 1) ^ 1)) * 16384;
      stage_tile<64, 512>((const char*)Kw  + (kbase + (long)(kt+64)*64)*2, 128,  nxt, tid);
      stage_tile<64, 512>((const char*)Vtw + (vbase + kt+64)*2,            4096, nxt + 8192, tid);
      asm volatile("s_waitcnt vmcnt(2)" ::: "memory");
    } else {
      asm volatile("s_waitcnt vmcnt(0)" ::: "memory");
    }
    __builtin_amdgcn_s_barrier();
    char* Klds = cur, *Vlds = cur + 8192;

    half8 kf[4][2];
    #pragma unroll
    for (int t = 0; t < 4; ++t)
      #pragma unroll
      for (int kk = 0; kk < 2; ++kk){
        int r = t*16 + lm;
        kf[t][kk] = *(const half8*)(Klds + r*128 + ((kk*64 + g*16) ^ ((r & 7) << 4)));
      }

    // S^T tiles: lane holds S[q=lm][kpos = kt + t*16 + g*4 + r]  (Q pre-scaled 1/8)
    f32x4 sc[4];
    #pragma unroll
    for (int t = 0; t < 4; ++t){
      f32x4 z = {0.f, 0.f, 0.f, 0.f};
      z = __builtin_amdgcn_mfma_f32_16x16x32_f16(kf[t][0], aQ[0], z, 0, 0, 0);
      z = __builtin_amdgcn_mfma_f32_16x16x32_f16(kf[t][1], aQ[1], z, 0, 0, 0);
      sc[t] = z;
    }
    // online softmax with defer-max (skip rescale while max grows < 8)
    float pm = sc[0][0];
    #pragma unroll
    for (int t = 0; t < 4; ++t)
      #pragma unroll
      for (int r = 0; r < 4; ++r) pm = fmaxf(pm, sc[t][r]);
    pm = fmaxf(pm, __shfl_xor(pm, 16));
    pm = fmaxf(pm, __shfl_xor(pm, 32));
    if (!__all(pm <= mrun + 8.0f)){
      float mnew = fmaxf(mrun, pm);
      float fac  = __expf(mrun - mnew);
      lrun *= fac;
      float frow[4];
      #pragma unroll
      for (int r = 0; r < 4; ++r) frow[r] = __shfl(fac, (lane & 48) | (g*4 + r));
      #pragma unroll
      for (int di = 0; di < 4; ++di){
        O[di][0] *= frow[0]; O[di][1] *= frow[1];
        O[di][2] *= frow[2]; O[di][3] *= frow[3];
      }
      mrun = mnew;
    }
    float ls = 0.f;
    #pragma unroll
    for (int t = 0; t < 4; ++t)
      #pragma unroll
      for (int r = 0; r < 4; ++r){ float pv = __expf(sc[t][r] - mrun); sc[t][r] = pv; ls += pv; }
    ls += __shfl_xor(ls, 16);
    ls += __shfl_xor(ls, 32);
    lrun += ls;

    // pack P (rtz pair-convert): pa[kh][j*4+r] = sc[kh*2+j][r]
    half8 pa[2];
    #pragma unroll
    for (int kh = 0; kh < 2; ++kh)
      #pragma unroll
      for (int j = 0; j < 2; ++j){
        int t = kh*2 + j;
        half2v p01 = __builtin_bit_cast(half2v, __builtin_amdgcn_cvt_pkrtz(sc[t][0], sc[t][1]));
        half2v p23 = __builtin_bit_cast(half2v, __builtin_amdgcn_cvt_pkrtz(sc[t][2], sc[t][3]));
        pa[kh][j*4+0] = p01[0]; pa[kh][j*4+1] = p01[1];
        pa[kh][j*4+2] = p23[0]; pa[kh][j*4+3] = p23[1];
      }
    // PV: O[q][d] += P[q][kpos] * V[kpos][d]
    #pragma unroll
    for (int di = 0; di < 4; ++di){
      int d = di*16 + lm;
      int swz = (d & 7) << 4;
      #pragma unroll
      for (int kh = 0; kh < 2; ++kh){
        half4 lo = *(const half4*)(Vlds + d*128 + ((kh*64 + g*8)      ^ swz));
        half4 hi = *(const half4*)(Vlds + d*128 + ((kh*64 + g*8 + 32) ^ swz));
        half8 vf = { lo[0], lo[1], lo[2], lo[3], hi[0], hi[1], hi[2], hi[3] };
        O[di] = __builtin_amdgcn_mfma_f32_16x16x32_f16(pa[kh], vf, O[di], 0, 0, 0);
      }
    }
    __builtin_amdgcn_s_barrier();
  }

  const int b = bh >> 4, h = bh & 15;
  float inv = 1.f / lrun;
  float irow[4];
  #pragma unroll
  for (int r = 0; r < 4; ++r) irow[r] = __shfl(inv, (lane & 48) | (g*4 + r));
  #pragma unroll
  for (int di = 0; di < 4; ++di)
    #pragma unroll
    for (int r = 0; r < 4; ++r){
      long q = q0 + g*4 + r;
      AO[((long)b*1024 + q)*1024 + h*64 + di*16 + lm] = f2h(O[di][r] * irow[r]);
    }
}

// O-projection: out = AO @ Wo^T + bo, f32 output. 512 blocks, chunked XCD map.
__global__ __launch_bounds__(256, 3)
void gemm_o(const u16* __restrict__ A, const u16* __restrict__ Bt,
            const float* __restrict__ bias, float* __restrict__ outF)
{
  __shared__ __align__(128) char lds[49152];
  const int tid = threadIdx.x, lane = tid & 63, w = tid >> 6;
  const int g = lane >> 4, lm = lane & 15;
  int bid = (blockIdx.x & 7) * 64 + (blockIdx.x >> 3);    // 512 = 8 * 64
  const int rb = bid >> 3, cb = bid & 7;
  const int row0 = rb * 64, col0 = cb * 128;

  f32x4 acc[2][4];
  #pragma unroll
  for (int i = 0; i < 2; ++i)
    #pragma unroll
    for (int j = 0; j < 4; ++j) acc[i][j] = {0.f, 0.f, 0.f, 0.f};

  gemm64_pipe(A, Bt, 1024, row0, col0, tid, lds, acc);

  const int wr = (w >> 1) * 32, wc = (w & 1) * 64;
  #pragma unroll
  for (int mi = 0; mi < 2; ++mi)
    #pragma unroll
    for (int ni = 0; ni < 4; ++ni){
      int n = col0 + wc + ni*16 + lm;
      float bvv = bias[n];
      #pragma unroll
      for (int r = 0; r < 4; ++r){
        int m = row0 + wr + mi*16 + g*4 + r;
        outF[(long)m * 1024 + n] = acc[mi][ni][r] + bvv;
      }
    }
}

extern "C" void kernel_launch(void* const* d_in, const int* in_sizes, int n_in,
                              void* d_out, int out_size, void* d_ws, size_t ws_size,
                              hipStream_t stream)
{
  const float* query = (const float*)d_in[0];
  const float* key   = (const float*)d_in[1];
  const float* value = (const float*)d_in[2];
  const float* Wq = (const float*)d_in[3];
  const float* bq = (const float*)d_in[4];
  const float* Wk = (const float*)d_in[5];
  const float* bk = (const float*)d_in[6];
  const float* Wv = (const float*)d_in[7];
  const float* bv = (const float*)d_in[8];
  const float* Wo = (const float*)d_in[9];
  const float* bo = (const float*)d_in[10];
  float* out = (float*)d_out;

  char* p = (char*)d_ws;
  auto alloc = [&](long bytes){ char* r = p; p += bytes; return r; };
  u16* qH  = (u16*)alloc( 8l<<20);   // [4096][1024] fp16
  u16* kH  = (u16*)alloc(12l<<20);   // [8192][768]
  u16* vH  = (u16*)alloc(12l<<20);   // [8192][768]
  u16* WqH = (u16*)alloc( 2l<<20);   // [1024][1024]
  u16* WkH = (u16*)alloc( 2l<<20);   // [1024][768]
  u16* WvH = (u16*)alloc( 2l<<20);   // [1024][768]
  u16* WoH = (u16*)alloc( 2l<<20);   // [1024][1024]
  u16* Qw  = (u16*)alloc( 8l<<20);   // [64][1024][64]
  u16* Kw  = (u16*)alloc(16l<<20);   // [64][2048][64]
  u16* Vtw = (u16*)alloc(16l<<20);   // [64][64][2048]
  u16* AO  = (u16*)alloc( 8l<<20);   // [4096][1024]

  Cvt7 ca;
  ca.seg[0] = { query, qH,  4096*1024/4 };
  ca.seg[1] = { key,   kH,  8192*768/4  };
  ca.seg[2] = { value, vH,  8192*768/4  };
  ca.seg[3] = { Wq,    WqH, 1024*1024/4 };
  ca.seg[4] = { Wk,    WkH, 1024*768/4  };
  ca.seg[5] = { Wv,    WvH, 1024*768/4  };
  ca.seg[6] = { Wo,    WoH, 1024*1024/4 };
  cvt_f32_f16<<<dim3(512, 7), 256, 0, stream>>>(ca);

  qkv_proj<<<dim3(2560), dim3(256), 0, stream>>>(qH, kH, vH, WqH, WkH, WvH,
                                                 bq, bk, bv, Qw, Kw, Vtw);
  attn_fused<<<dim3(512), dim3(512), 0, stream>>>(Qw, Kw, Vtw, AO);
  gemm_o<<<dim3(512), dim3(256), 0, stream>>>(AO, WoH, bo, out);
}